// Round 1
// baseline (5423.304 us; speedup 1.0000x reference)
//
#include <hip/hip_runtime.h>
#include <math.h>

// ConvGRU scan: T=64 steps, N=128 independent batch chains.
// One workgroup (256 threads) per batch item; hidden state lives in LDS
// across all timesteps. All fp32 this round (correctness baseline).

#define CC 32            // hidden channels
#define WID 7            // spatial width
#define AA 8             // num actions
#define TT 64            // timesteps
#define NBATCH 128       // batch
#define SS (WID*WID)     // 49
#define HH (CC*SS)       // 1568
#define PP 81            // 9*9 padded image
#define CIN1 (AA+CC)     // 40

// conv 3x3 SAME over 7x7, CIN input channels (padded 9x9 LDS images),
// each wave computes 8 output channels (co = wave*8 + j), lanes 0..48 = spatial.
// MODE 0: +bias, relu, store padded into sOut[co*81 + ...]
// MODE 1: +bias, sigmoid, store flat sOut[co*49 + s]
// MODE 2: +bias, tanh,    store flat sOut[co*49 + s]
template<int CIN, int MODE>
__device__ __forceinline__ void conv3x3(const float* __restrict__ W,
                                        const float* __restrict__ b,
                                        const float* sIn, float* sOut,
                                        int wv, int lane)
{
    const int s = (lane < SS) ? lane : (SS - 1);
    const int y = s / WID, x = s - y * WID;
    const float* ib0 = sIn + y * 9 + x;   // top-left of 3x3 window in padded coords

    float acc[8];
#pragma unroll
    for (int j = 0; j < 8; ++j) acc[j] = 0.f;

    for (int ci = 0; ci < CIN; ++ci) {
        const float* ib = ib0 + ci * PP;
        float inv[9];
#pragma unroll
        for (int r = 0; r < 3; ++r)
#pragma unroll
            for (int c = 0; c < 3; ++c)
                inv[r * 3 + c] = ib[r * 9 + c];
#pragma unroll
        for (int j = 0; j < 8; ++j) {
            // wv is wave-uniform (readfirstlane'd) -> scalar (s_load) weight reads
            const float* wp = W + ((size_t)((wv * 8 + j) * CIN + ci)) * 9;
            float a0 = acc[j];
#pragma unroll
            for (int k = 0; k < 9; ++k)
                a0 = fmaf(inv[k], wp[k], a0);
            acc[j] = a0;
        }
    }

    if (lane < SS) {
#pragma unroll
        for (int j = 0; j < 8; ++j) {
            const int co = wv * 8 + j;
            const float v = acc[j] + b[co];
            if (MODE == 0)
                sOut[co * PP + (y + 1) * 9 + (x + 1)] = fmaxf(v, 0.f);
            else if (MODE == 1)
                sOut[co * SS + s] = 1.0f / (1.0f + __expf(-v));
            else
                sOut[co * SS + s] = tanhf(v);
        }
    }
}

__global__ __launch_bounds__(256, 1)
void convgru_scan_fp32(const float* __restrict__ x, const float* __restrict__ hxs,
                       const float* __restrict__ att, const float* __restrict__ masks,
                       const float* __restrict__ pact,
                       const float* __restrict__ Wr1, const float* __restrict__ br1,
                       const float* __restrict__ Wr2, const float* __restrict__ br2,
                       const float* __restrict__ Wu1, const float* __restrict__ bu1,
                       const float* __restrict__ Wu2, const float* __restrict__ bu2,
                       const float* __restrict__ Wo1, const float* __restrict__ bo1,
                       const float* __restrict__ Wo2, const float* __restrict__ bo2,
                       float* __restrict__ out)
{
    __shared__ float sA[CIN1 * PP];   // padded conv1 input (stacked / stacked2)
    __shared__ float sB[CC * PP];     // padded conv1 output (gate hidden)
    __shared__ float sH[HH];          // hidden / prev
    __shared__ float sU[HH];          // update (post-sigmoid)
    __shared__ float sR[HH];          // reset (post-sigmoid)
    __shared__ float sO[HH];          // out_in (post-tanh)
    __shared__ float sInp[AA];        // action*mask channel values

    const int n = blockIdx.x;
    const int tid = threadIdx.x;
    const int wv = __builtin_amdgcn_readfirstlane(tid >> 6);
    const int lane = tid & 63;

    float* out_pmu = out;
    float* out_att = out + (size_t)TT * NBATCH * HH;
    float* out_h   = out + (size_t)2 * TT * NBATCH * HH;

    // zero padded buffers once: borders stay 0 forever (only interiors written)
    for (int i = tid; i < CIN1 * PP; i += 256) sA[i] = 0.f;
    for (int i = tid; i < CC * PP; i += 256) sB[i] = 0.f;
    for (int i = tid; i < HH; i += 256) sH[i] = hxs[(size_t)n * HH + i];
    __syncthreads();

    for (int t = 0; t < TT; ++t) {
        const float* xt = x   + ((size_t)t * NBATCH + n) * HH;
        const float* at = att + ((size_t)t * NBATCH + n) * HH;
        const float mi = masks[t * NBATCH + n];

        // 1. hidden = h*m + x*(1-m); inp channel scalars
        for (int i = tid; i < HH; i += 256)
            sH[i] = sH[i] * mi + xt[i] * (1.f - mi);
        if (tid < AA)
            sInp[tid] = pact[((size_t)t * NBATCH + n) * AA + tid] * mi;
        __syncthreads();

        // 2. stacked = [inp(8ch, spatially const), prev(32ch)] into padded sA
        for (int i = tid; i < CIN1 * SS; i += 256) {
            const int c = i / SS, s = i - c * SS;
            const int y = s / WID, xx = s - y * WID;
            const float v = (c < AA) ? sInp[c] : sH[(c - AA) * SS + s];
            sA[c * PP + (y + 1) * 9 + (xx + 1)] = v;
        }
        __syncthreads();

        // update gate: conv(40->32)+relu, conv(32->32)+sigmoid
        conv3x3<CIN1, 0>(Wu1, bu1, sA, sB, wv, lane); __syncthreads();
        conv3x3<CC,   1>(Wu2, bu2, sB, sU, wv, lane); __syncthreads();

        // reset gate
        conv3x3<CIN1, 0>(Wr1, br1, sA, sB, wv, lane); __syncthreads();
        conv3x3<CC,   1>(Wr2, br2, sB, sR, wv, lane); __syncthreads();

        // 3. stacked2: replace prev channels with prev*reset (inp channels unchanged)
        for (int i = tid; i < CC * SS; i += 256) {
            const int c = i / SS, s = i - c * SS;
            const int y = s / WID, xx = s - y * WID;
            sA[(c + AA) * PP + (y + 1) * 9 + (xx + 1)] = sH[i] * sR[i];
        }
        __syncthreads();

        // output gate: conv(40->32)+relu, conv(32->32)+tanh
        conv3x3<CIN1, 0>(Wo1, bo1, sA, sB, wv, lane); __syncthreads();
        conv3x3<CC,   2>(Wo2, bo2, sB, sO, wv, lane); __syncthreads();

        // 4. epilogue: p_mu, attended, carry
        const size_t obase = ((size_t)t * NBATCH + n) * HH;
        for (int i = tid; i < HH; i += 256) {
            const float u  = sU[i];
            const float pm = sH[i] * (1.f - u) + sO[i] * u;
            out_pmu[obase + i] = pm;
            const float a  = at[i];
            const float av = xt[i] * a + pm * (1.f - a);
            out_att[obase + i] = av;
            sH[i] = av;   // carry = attended
        }
        __syncthreads();
    }

    for (int i = tid; i < HH; i += 256)
        out_h[(size_t)n * HH + i] = sH[i];
}

extern "C" void kernel_launch(void* const* d_in, const int* in_sizes, int n_in,
                              void* d_out, int out_size, void* d_ws, size_t ws_size,
                              hipStream_t stream)
{
    const float* x    = (const float*)d_in[0];
    const float* hxs  = (const float*)d_in[1];
    const float* att  = (const float*)d_in[2];
    const float* mks  = (const float*)d_in[3];
    const float* pact = (const float*)d_in[4];
    const float* Wr1  = (const float*)d_in[5];
    const float* br1  = (const float*)d_in[6];
    const float* Wr2  = (const float*)d_in[7];
    const float* br2  = (const float*)d_in[8];
    const float* Wu1  = (const float*)d_in[9];
    const float* bu1  = (const float*)d_in[10];
    const float* Wu2  = (const float*)d_in[11];
    const float* bu2  = (const float*)d_in[12];
    const float* Wo1  = (const float*)d_in[13];
    const float* bo1  = (const float*)d_in[14];
    const float* Wo2  = (const float*)d_in[15];
    const float* bo2  = (const float*)d_in[16];

    convgru_scan_fp32<<<dim3(NBATCH), dim3(256), 0, stream>>>(
        x, hxs, att, mks, pact,
        Wr1, br1, Wr2, br2, Wu1, bu1, Wu2, bu2, Wo1, bo1, Wo2, bo2,
        (float*)d_out);
}

// Round 2
// 395.122 us; speedup vs baseline: 13.7256x; 13.7256x over previous
//
#include <hip/hip_runtime.h>
#include <math.h>

// ConvGRU scan via bf16 MFMA. 128 blocks (1 per batch item) x 768 threads
// (12 waves: 4 u-gate, 4 r-gate, 4 o-gate). Hidden state + images in LDS.
// Convs = GEMM out[32co][49s] = Wt[co][k] * img[k][s], k=(tap,ci) fused,
// MFMA 16x16x32 bf16, weights preloaded in VGPRs per gate-specialized wave.

#define TT 64
#define NB 128
#define CC 32
#define AA 8
#define SS 49
#define HH 1568
#define CIN1 40
#define K1 360
#define K1P 384     // 12 k-blocks of 32
#define NKB1 12
#define K2 288      // 9 k-blocks exactly
#define NKB2 9
#define IST 40      // image row stride in shorts per spatial position
#define NPOS 81     // 9x9 padded
#define NTHR 768

typedef short bf16x8 __attribute__((ext_vector_type(8)));
typedef short bf16x4 __attribute__((ext_vector_type(4)));
typedef float f32x4 __attribute__((ext_vector_type(4)));

struct SMEM {
  union {
    short staging[CC * K1P];          // 12288 shorts (weight transpose scratch)
    struct {
      short stacked[NPOS * IST];      // conv1 input: chans 0..7 inp, 8..39 prev
      short img_u[NPOS * IST];        // u1-relu out / o1-relu out (reused)
      short img_r[NPOS * IST];        // r1-relu out
    } im;
  } u;
  float sH[HH];                       // hidden (prev), f32
  float sU[HH];                       // sigmoid(update)
  float sO[HH];                       // tanh(out_in)
  float bias[6 * CC];                 // bu1,bu2,br1,br2,bo1,bo2
};

__device__ __forceinline__ short f2bf(float v) {
  union { float f; unsigned u; } a; a.f = v;
  unsigned r = a.u + 0x7FFFu + ((a.u >> 16) & 1u);
  return (short)(r >> 16);
}
__device__ __forceinline__ float sigm(float v) { return 1.f / (1.f + __expf(-v)); }
__device__ __forceinline__ float tanhfast(float v) { return 2.f / (1.f + __expf(-2.f * v)) - 1.f; }

template<int NKB, bool PAD>
__device__ __forceinline__ f32x4 conv_acc(const short* img, const bf16x8 (&fA)[NKB],
                                          const int (&offs)[NKB], int base, int fg)
{
  f32x4 acc = {0.f, 0.f, 0.f, 0.f};
#pragma unroll
  for (int b = 0; b < NKB; ++b) {
    int sa = base + offs[b];
    if (PAD && b == NKB - 1) sa = (fg == 0) ? sa : 0;  // pad k>=360 -> zero border cell
    bf16x8 bv = *(const bf16x8*)(img + sa);
    acc = __builtin_amdgcn_mfma_f32_16x16x32_bf16(fA[b], bv, acc, 0, 0, 0);
  }
  return acc;
}

__global__ __launch_bounds__(NTHR)
void convgru_mfma(const float* __restrict__ x, const float* __restrict__ hxs,
                  const float* __restrict__ att, const float* __restrict__ masks,
                  const float* __restrict__ pact,
                  const float* __restrict__ Wr1, const float* __restrict__ br1,
                  const float* __restrict__ Wr2, const float* __restrict__ br2,
                  const float* __restrict__ Wu1, const float* __restrict__ bu1,
                  const float* __restrict__ Wu2, const float* __restrict__ bu2,
                  const float* __restrict__ Wo1, const float* __restrict__ bo1,
                  const float* __restrict__ Wo2, const float* __restrict__ bo2,
                  float* __restrict__ out)
{
  __shared__ SMEM sm;
  const int n = blockIdx.x;
  const int tid = threadIdx.x;
  const int w = tid >> 6;
  const int lane = tid & 63;
  const int gate = w >> 2;            // 0 u, 1 r, 2 o
  const int wq = w & 3;
  const int mtile = wq & 1;
  const int ntbase = (wq >> 1) * 2;
  const int fg = lane >> 4;
  const int col = lane & 15;
  const int co0 = mtile * 16 + fg * 4;

  // ---- bias staging
  if (tid < 6 * CC) {
    const float* bsrc[6] = {bu1, bu2, br1, br2, bo1, bo2};
    sm.bias[tid] = bsrc[tid >> 5][tid & 31];
  }

  // ---- weight transpose staging + per-wave A-frag preload
  bf16x8 fA1[NKB1], fA2[NKB2];
  {
    const float* wsrc[6] = {Wu1, Wr1, Wo1, Wu2, Wr2, Wo2};
#pragma unroll
    for (int cv = 0; cv < 6; ++cv) {
      __syncthreads();
      for (int i = tid; i < CC * K1P; i += NTHR) sm.u.staging[i] = 0;
      __syncthreads();
      const float* wp = wsrc[cv];
      if (cv < 3) {
        for (int i = tid; i < CC * CIN1 * 9; i += NTHR) {
          int co = i / (CIN1 * 9); int rem = i - co * (CIN1 * 9);
          int ci = rem / 9; int tap = rem - ci * 9;
          int k = tap * CIN1 + ci;
          sm.u.staging[(co * K1P + k) ^ ((co & 7) << 3)] = f2bf(wp[i]);
        }
      } else {
        for (int i = tid; i < CC * CC * 9; i += NTHR) {
          int co = i / (CC * 9); int rem = i - co * (CC * 9);
          int ci = rem / 9; int tap = rem - ci * 9;
          int k = tap * CC + ci;
          sm.u.staging[(co * K2 + k) ^ ((co & 7) << 3)] = f2bf(wp[i]);
        }
      }
      __syncthreads();
      if (gate == (cv % 3)) {
        int fco = mtile * 16 + col;
        if (cv < 3) {
#pragma unroll
          for (int b = 0; b < NKB1; ++b) {
            int sadr = (fco * K1P + b * 32 + fg * 8) ^ ((fco & 7) << 3);
            fA1[b] = *(const bf16x8*)&sm.u.staging[sadr];
          }
        } else {
#pragma unroll
          for (int b = 0; b < NKB2; ++b) {
            int sadr = (fco * K2 + b * 32 + fg * 8) ^ ((fco & 7) << 3);
            fA2[b] = *(const bf16x8*)&sm.u.staging[sadr];
          }
        }
      }
    }
  }
  __syncthreads();

  // ---- zero images (borders / pad chans must stay 0)
  for (int i = tid; i < 3 * NPOS * IST; i += NTHR) sm.u.staging[i] = 0;
  // ---- hidden load
  for (int i = tid; i < HH; i += NTHR) sm.sH[i] = hxs[(size_t)n * HH + i];

  // ---- per-lane spatial precompute (static across t)
  int ssv[2], base_in[2], pos_out[2]; bool valid[2];
#pragma unroll
  for (int j = 0; j < 2; ++j) {
    int s = (ntbase + j) * 16 + col;
    valid[j] = (s < SS);
    int sc = valid[j] ? s : (SS - 1);
    ssv[j] = sc;
    int yy = sc / 7, xx = sc - yy * 7;
    base_in[j] = (yy * 9 + xx) * IST;
    pos_out[j] = ((yy + 1) * 9 + (xx + 1)) * IST;
  }
  int offs1[NKB1];
#pragma unroll
  for (int b = 0; b < NKB1; ++b) {
    int k0 = b * 32 + fg * 8;
    int kk = (k0 < K1) ? k0 : 0;
    int tap = kk / CIN1, ci0 = kk - tap * CIN1;
    int r = tap / 3, c = tap - 3 * r;
    offs1[b] = (r * 9 + c) * IST + ci0;
  }
  int offs2[NKB2];
#pragma unroll
  for (int b = 0; b < NKB2; ++b) {
    int r = b / 3, c = b - 3 * r;
    offs2[b] = (r * 9 + c) * IST + fg * 8;
  }

  float* out_pmu = out;
  float* out_att = out + (size_t)TT * NB * HH;
  float* out_h   = out + (size_t)2 * TT * NB * HH;

  __syncthreads();

  // ---- build step-0 hidden + stacked
  {
    const float m0 = masks[n];
    const float* x0 = x + (size_t)n * HH;
    for (int i = tid; i < HH; i += NTHR) {
      float h = sm.sH[i] * m0 + x0[i] * (1.f - m0);
      sm.sH[i] = h;
      int co = i / SS, s = i - co * SS;
      int yy = s / 7, xx = s - yy * 7;
      sm.u.im.stacked[((yy + 1) * 9 + xx + 1) * IST + AA + co] = f2bf(h);
    }
    const float* pa0 = pact + (size_t)n * AA;
    for (int i = tid; i < AA * SS; i += NTHR) {
      int ch = i & 7, s = i >> 3;
      int yy = s / 7, xx = s - yy * 7;
      sm.u.im.stacked[((yy + 1) * 9 + xx + 1) * IST + ch] = f2bf(pa0[ch] * m0);
    }
  }
  __syncthreads();

  for (int t = 0; t < TT; ++t) {
    const float* xt = x   + ((size_t)(t * NB) + n) * HH;
    const float* atp = att + ((size_t)(t * NB) + n) * HH;

    // P1: u,r conv1 (40->32) + relu -> img_u / img_r
    if (gate < 2) {
      short* imgOut = gate ? sm.u.im.img_r : sm.u.im.img_u;
      const float* bb = sm.bias + gate * 2 * CC;
#pragma unroll
      for (int j = 0; j < 2; ++j) {
        f32x4 a = conv_acc<NKB1, true>(sm.u.im.stacked, fA1, offs1, base_in[j], fg);
        if (valid[j]) {
          bf16x4 pk;
#pragma unroll
          for (int i2 = 0; i2 < 4; ++i2)
            pk[i2] = f2bf(fmaxf(a[i2] + bb[co0 + i2], 0.f));
          *(bf16x4*)&imgOut[pos_out[j] + co0] = pk;
        }
      }
    }
    __syncthreads();

    // P2: u conv2 -> sigmoid -> sU ; r conv2 -> sigmoid*prev -> stacked prev-chans
    if (gate == 0) {
      const float* bb = sm.bias + 1 * CC;
#pragma unroll
      for (int j = 0; j < 2; ++j) {
        f32x4 a = conv_acc<NKB2, false>(sm.u.im.img_u, fA2, offs2, base_in[j], fg);
        if (valid[j]) {
#pragma unroll
          for (int i2 = 0; i2 < 4; ++i2)
            sm.sU[(co0 + i2) * SS + ssv[j]] = sigm(a[i2] + bb[co0 + i2]);
        }
      }
    } else if (gate == 1) {
      const float* bb = sm.bias + 3 * CC;
#pragma unroll
      for (int j = 0; j < 2; ++j) {
        f32x4 a = conv_acc<NKB2, false>(sm.u.im.img_r, fA2, offs2, base_in[j], fg);
        if (valid[j]) {
          bf16x4 pk;
#pragma unroll
          for (int i2 = 0; i2 < 4; ++i2) {
            float rv = sigm(a[i2] + bb[co0 + i2]);
            float pv = sm.sH[(co0 + i2) * SS + ssv[j]];
            pk[i2] = f2bf(pv * rv);
          }
          *(bf16x4*)&sm.u.im.stacked[pos_out[j] + AA + co0] = pk;
        }
      }
    }
    __syncthreads();

    // P3: o conv1 on stacked2 -> relu -> img_u (u done with it)
    if (gate == 2) {
      const float* bb = sm.bias + 4 * CC;
#pragma unroll
      for (int j = 0; j < 2; ++j) {
        f32x4 a = conv_acc<NKB1, true>(sm.u.im.stacked, fA1, offs1, base_in[j], fg);
        if (valid[j]) {
          bf16x4 pk;
#pragma unroll
          for (int i2 = 0; i2 < 4; ++i2)
            pk[i2] = f2bf(fmaxf(a[i2] + bb[co0 + i2], 0.f));
          *(bf16x4*)&sm.u.im.img_u[pos_out[j] + co0] = pk;
        }
      }
    }
    __syncthreads();

    // P4: o conv2 -> tanh -> sO
    if (gate == 2) {
      const float* bb = sm.bias + 5 * CC;
#pragma unroll
      for (int j = 0; j < 2; ++j) {
        f32x4 a = conv_acc<NKB2, false>(sm.u.im.img_u, fA2, offs2, base_in[j], fg);
        if (valid[j]) {
#pragma unroll
          for (int i2 = 0; i2 < 4; ++i2)
            sm.sO[(co0 + i2) * SS + ssv[j]] = tanhfast(a[i2] + bb[co0 + i2]);
        }
      }
    }
    __syncthreads();

    // P5: all waves: epilogue(t) + build(t+1), coalesced global I/O
    {
      const size_t obase = ((size_t)(t * NB) + n) * HH;
      const bool last = (t == TT - 1);
      const float m2 = last ? 0.f : masks[(t + 1) * NB + n];
      const float* xn = last ? xt : (x + ((size_t)((t + 1) * NB) + n) * HH);
      for (int i = tid; i < HH; i += NTHR) {
        float uv = sm.sU[i];
        float ov = sm.sO[i];
        float pv = sm.sH[i];
        float pm = pv * (1.f - uv) + ov * uv;
        out_pmu[obase + i] = pm;
        float xv = xt[i], av = atp[i];
        float at2 = xv * av + pm * (1.f - av);
        out_att[obase + i] = at2;
        if (last) {
          out_h[(size_t)n * HH + i] = at2;
        } else {
          float h = at2 * m2 + xn[i] * (1.f - m2);
          sm.sH[i] = h;
          int co = i / SS, s = i - co * SS;
          int yy = s / 7, xx = s - yy * 7;
          sm.u.im.stacked[((yy + 1) * 9 + xx + 1) * IST + AA + co] = f2bf(h);
        }
      }
      if (!last) {
        const float* pa2 = pact + ((size_t)((t + 1) * NB) + n) * AA;
        for (int i = tid; i < AA * SS; i += NTHR) {
          int ch = i & 7, s = i >> 3;
          int yy = s / 7, xx = s - yy * 7;
          sm.u.im.stacked[((yy + 1) * 9 + xx + 1) * IST + ch] = f2bf(pa2[ch] * m2);
        }
      }
    }
    __syncthreads();
  }
}

extern "C" void kernel_launch(void* const* d_in, const int* in_sizes, int n_in,
                              void* d_out, int out_size, void* d_ws, size_t ws_size,
                              hipStream_t stream)
{
  const float* x    = (const float*)d_in[0];
  const float* hxs  = (const float*)d_in[1];
  const float* att  = (const float*)d_in[2];
  const float* mks  = (const float*)d_in[3];
  const float* pact = (const float*)d_in[4];
  const float* Wr1  = (const float*)d_in[5];
  const float* br1  = (const float*)d_in[6];
  const float* Wr2  = (const float*)d_in[7];
  const float* br2  = (const float*)d_in[8];
  const float* Wu1  = (const float*)d_in[9];
  const float* bu1  = (const float*)d_in[10];
  const float* Wu2  = (const float*)d_in[11];
  const float* bu2  = (const float*)d_in[12];
  const float* Wo1  = (const float*)d_in[13];
  const float* bo1  = (const float*)d_in[14];
  const float* Wo2  = (const float*)d_in[15];
  const float* bo2  = (const float*)d_in[16];

  convgru_mfma<<<dim3(NB), dim3(NTHR), 0, stream>>>(
      x, hxs, att, mks, pact,
      Wr1, br1, Wr2, br2, Wu1, bu1, Wu2, bu2, Wo1, bo1, Wo2, bo2,
      (float*)d_out);
}

// Round 3
// 306.341 us; speedup vs baseline: 17.7035x; 1.2898x over previous
//
#include <hip/hip_runtime.h>
#include <math.h>

// ConvGRU scan, bf16 MFMA, 128 blocks x 512 threads (8 waves).
// Waves 0-3 = u gate, 4-7 = r gate; o-gate convs distributed across all 8.
// All global x/att I/O prefetched into registers at step start.

#define TT 64
#define NB 128
#define CC 32
#define AA 8
#define SS 49
#define HH 1568
#define CIN1 40
#define K1 360
#define K1P 384
#define NKB1 12
#define K2 288
#define NKB2 9
#define IST 40
#define NPOS 81
#define NTHR 512

typedef short bf16x8 __attribute__((ext_vector_type(8)));
typedef short bf16x4 __attribute__((ext_vector_type(4)));
typedef float f32x4 __attribute__((ext_vector_type(4)));

struct SMEM {
  union {
    short staging[CC * K1P];            // 12288 shorts, weight transpose scratch
    struct {
      short stacked[NPOS * IST];        // ci 0..7 = inp, 8..39 = prev (or prev*r)
      short img_u[NPOS * IST];          // u1 out / o1 out (reused)
      short img_r[NPOS * IST];          // r1 out
    } im;
  } u;
  float sH[HH];
  float sU[HH];
  float sO[HH];
  float bias[6 * CC];                   // bu1,bu2,br1,br2,bo1,bo2
};

__device__ __forceinline__ short f2bf(float v) {
  union { float f; unsigned u; } a; a.f = v;
  unsigned r = a.u + 0x7FFFu + ((a.u >> 16) & 1u);
  return (short)(r >> 16);
}
__device__ __forceinline__ float sigm(float v) { return 1.f / (1.f + __expf(-v)); }
__device__ __forceinline__ float tanhfast(float v) { return 2.f / (1.f + __expf(-2.f * v)) - 1.f; }

// dual accumulator chains (even/odd k-blocks) for MFMA latency hiding
template<int NKB, bool PAD>
__device__ __forceinline__ f32x4 conv_acc(const short* img, const bf16x8 (&fA)[NKB],
                                          const int (&offs)[NKB], int base, int fg)
{
  f32x4 a0 = {0.f, 0.f, 0.f, 0.f}, a1 = {0.f, 0.f, 0.f, 0.f};
#pragma unroll
  for (int b = 0; b < NKB; b += 2) {
    {
      int sa = base + offs[b];
      a0 = __builtin_amdgcn_mfma_f32_16x16x32_bf16(fA[b], *(const bf16x8*)(img + sa), a0, 0, 0, 0);
    }
    if (b + 1 < NKB) {
      int sa = base + offs[b + 1];
      if (PAD && (b + 1 == NKB - 1)) sa = (fg == 0) ? sa : 0;  // k>=360 pad -> zero border cell
      a1 = __builtin_amdgcn_mfma_f32_16x16x32_bf16(fA[b + 1], *(const bf16x8*)(img + sa), a1, 0, 0, 0);
    }
  }
  return a0 + a1;
}

__global__ __launch_bounds__(NTHR, 2)
void convgru_mfma(const float* __restrict__ x, const float* __restrict__ hxs,
                  const float* __restrict__ att, const float* __restrict__ masks,
                  const float* __restrict__ pact,
                  const float* __restrict__ Wr1, const float* __restrict__ br1,
                  const float* __restrict__ Wr2, const float* __restrict__ br2,
                  const float* __restrict__ Wu1, const float* __restrict__ bu1,
                  const float* __restrict__ Wu2, const float* __restrict__ bu2,
                  const float* __restrict__ Wo1, const float* __restrict__ bo1,
                  const float* __restrict__ Wo2, const float* __restrict__ bo2,
                  float* __restrict__ out)
{
  __shared__ SMEM sm;
  const int n = blockIdx.x;
  const int tid = threadIdx.x;
  const int w = __builtin_amdgcn_readfirstlane(tid >> 6);
  const int lane = tid & 63;
  const int gate = w >> 2;            // 0 = u, 1 = r
  const int wq = w & 3;
  const int mt = w & 1;               // mtile (gate jobs AND o job)
  const int sbase = (wq >> 1) * 2;    // gate stile base (covers sbase, sbase+1)
  const int stO = w >> 1;             // o-job stile
  const int fg = lane >> 4;
  const int col = lane & 15;
  const int co0 = mt * 16 + fg * 4;

  // ---- bias staging
  if (tid < 6 * CC) {
    const float* bsrc[6] = {bu1, bu2, br1, br2, bo1, bo2};
    sm.bias[tid] = bsrc[tid >> 5][tid & 31];
  }

  // ---- weight transpose staging + per-wave A-frag preload
  bf16x8 fG1[NKB1], fG2[NKB2], fO1[NKB1], fO2[NKB2];
  {
    const float* wsrc[6] = {Wu1, Wr1, Wo1, Wu2, Wr2, Wo2};
#pragma unroll
    for (int cv = 0; cv < 6; ++cv) {
      __syncthreads();
      for (int i = tid; i < CC * K1P; i += NTHR) sm.u.staging[i] = 0;
      __syncthreads();
      const float* wp = wsrc[cv];
      if (cv < 3) {
        for (int i = tid; i < CC * CIN1 * 9; i += NTHR) {
          int co = i / (CIN1 * 9); int rem = i - co * (CIN1 * 9);
          int ci = rem / 9; int tap = rem - ci * 9;
          sm.u.staging[(co * K1P + tap * CIN1 + ci) ^ ((co & 7) << 3)] = f2bf(wp[i]);
        }
      } else {
        for (int i = tid; i < CC * CC * 9; i += NTHR) {
          int co = i / (CC * 9); int rem = i - co * (CC * 9);
          int ci = rem / 9; int tap = rem - ci * 9;
          sm.u.staging[(co * K2 + tap * CC + ci) ^ ((co & 7) << 3)] = f2bf(wp[i]);
        }
      }
      __syncthreads();
      const int fco = mt * 16 + col;
      if (cv == 2) {
#pragma unroll
        for (int b = 0; b < NKB1; ++b)
          fO1[b] = *(const bf16x8*)&sm.u.staging[(fco * K1P + b * 32 + fg * 8) ^ ((fco & 7) << 3)];
      } else if (cv == 5) {
#pragma unroll
        for (int b = 0; b < NKB2; ++b)
          fO2[b] = *(const bf16x8*)&sm.u.staging[(fco * K2 + b * 32 + fg * 8) ^ ((fco & 7) << 3)];
      } else if (cv < 2) {
        if (gate == cv) {
#pragma unroll
          for (int b = 0; b < NKB1; ++b)
            fG1[b] = *(const bf16x8*)&sm.u.staging[(fco * K1P + b * 32 + fg * 8) ^ ((fco & 7) << 3)];
        }
      } else {
        if (gate == cv - 3) {
#pragma unroll
          for (int b = 0; b < NKB2; ++b)
            fG2[b] = *(const bf16x8*)&sm.u.staging[(fco * K2 + b * 32 + fg * 8) ^ ((fco & 7) << 3)];
        }
      }
    }
  }
  __syncthreads();
  // zero image region (borders / pad channels must stay 0 forever)
  for (int i = tid; i < CC * K1P; i += NTHR) sm.u.staging[i] = 0;

  // ---- per-lane spatial precompute (t-invariant)
  int sg[2], binG[2], poutG[2]; bool vG[2];
#pragma unroll
  for (int j = 0; j < 2; ++j) {
    int s = (sbase + j) * 16 + col;
    vG[j] = (s < SS); int sc = vG[j] ? s : (SS - 1); sg[j] = sc;
    int yy = sc / 7, xx = sc - yy * 7;
    binG[j] = (yy * 9 + xx) * IST;
    poutG[j] = ((yy + 1) * 9 + (xx + 1)) * IST;
  }
  int sOv, binO, poutO; bool vO;
  {
    int s = stO * 16 + col;
    vO = (s < SS); int sc = vO ? s : (SS - 1); sOv = sc;
    int yy = sc / 7, xx = sc - yy * 7;
    binO = (yy * 9 + xx) * IST;
    poutO = ((yy + 1) * 9 + (xx + 1)) * IST;
  }
  int offs1[NKB1];
#pragma unroll
  for (int b = 0; b < NKB1; ++b) {
    int k0 = b * 32 + fg * 8;
    int kk = (k0 < K1) ? k0 : 0;
    int tap = kk / CIN1, ci0 = kk - tap * CIN1;
    int r = tap / 3, c = tap - 3 * r;
    offs1[b] = (r * 9 + c) * IST + ci0;
  }
  int offs2[NKB2];
#pragma unroll
  for (int b = 0; b < NKB2; ++b) {
    int r = b / 3, c = b - 3 * r;
    offs2[b] = (r * 9 + c) * IST + fg * 8;
  }

  // ---- epilogue index precompute (t-invariant)
  int eidx[4], stAddr[4]; bool eval[4];
#pragma unroll
  for (int j = 0; j < 4; ++j) {
    int i = tid + j * NTHR;
    eval[j] = (i < HH);
    int ii = eval[j] ? i : 0;
    eidx[j] = ii;
    int co = ii / SS, s = ii - co * SS;
    int yy = s / 7, xx = s - yy * 7;
    stAddr[j] = ((yy + 1) * 9 + (xx + 1)) * IST + AA + co;
  }
  int inpAddr; const bool inpV = (tid < AA * SS);
  {
    int i = inpV ? tid : 0;
    int ch = i & 7, s = i >> 3;
    int yy = s / 7, xx = s - yy * 7;
    inpAddr = ((yy + 1) * 9 + (xx + 1)) * IST + ch;
  }

  float* out_pmu = out;
  float* out_att = out + (size_t)TT * NB * HH;
  float* out_h   = out + (size_t)2 * TT * NB * HH;

  __syncthreads();

  // ---- step-0 build: hidden + stacked + x carry regs
  float xcar[4];
  {
    const float m0 = masks[n];
    const float* x0 = x + (size_t)n * HH;
    const float* h0 = hxs + (size_t)n * HH;
#pragma unroll
    for (int j = 0; j < 4; ++j) if (eval[j]) {
      float xv = x0[eidx[j]];
      float h = h0[eidx[j]] * m0 + xv * (1.f - m0);
      sm.sH[eidx[j]] = h;
      sm.u.im.stacked[stAddr[j]] = f2bf(h);
      xcar[j] = xv;
    }
    if (inpV) sm.u.im.stacked[inpAddr] = f2bf(pact[(size_t)n * AA + (tid & 7)] * m0);
  }
  __syncthreads();

  for (int t = 0; t < TT; ++t) {
    const bool last = (t == TT - 1);
    const size_t obase = ((size_t)(t * NB) + n) * HH;

    // ---- prefetch next-x / att(t) / masks(t+1) / pact(t+1): issued now,
    //      consumed in P5 (hidden under 4 conv phases)
    const float* atp = att + obase;
    const int tn = last ? t : (t + 1);
    const float* xnp = x + ((size_t)(tn * NB) + n) * HH;
    float xnv[4], avv[4];
#pragma unroll
    for (int j = 0; j < 4; ++j) {
      avv[j] = atp[eidx[j]];
      xnv[j] = xnp[eidx[j]];
    }
    const float m2 = last ? 0.f : masks[(t + 1) * NB + n];
    float pav = 0.f;
    if (inpV && !last) pav = pact[((size_t)((t + 1) * NB) + n) * AA + (tid & 7)] * m2;

    // ---- P1: gate conv1 (u1 by u-waves, r1 by r-waves), all 8 waves busy
    {
      short* imgOut = gate ? sm.u.im.img_r : sm.u.im.img_u;
      const float* bb = sm.bias + gate * 2 * CC;
#pragma unroll
      for (int j = 0; j < 2; ++j) {
        f32x4 a = conv_acc<NKB1, true>(sm.u.im.stacked, fG1, offs1, binG[j], fg);
        if (vG[j]) {
          bf16x4 pk;
#pragma unroll
          for (int q = 0; q < 4; ++q) pk[q] = f2bf(fmaxf(a[q] + bb[co0 + q], 0.f));
          *(bf16x4*)&imgOut[poutG[j] + co0] = pk;
        }
      }
    }
    __syncthreads();

    // ---- P2: gate conv2 (u2 -> sU; r2 -> prev*r into stacked IN PLACE)
    if (gate == 0) {
      const float* bb = sm.bias + CC;
#pragma unroll
      for (int j = 0; j < 2; ++j) {
        f32x4 a = conv_acc<NKB2, false>(sm.u.im.img_u, fG2, offs2, binG[j], fg);
        if (vG[j]) {
#pragma unroll
          for (int q = 0; q < 4; ++q)
            sm.sU[(co0 + q) * SS + sg[j]] = sigm(a[q] + bb[co0 + q]);
        }
      }
    } else {
      const float* bb = sm.bias + 3 * CC;
#pragma unroll
      for (int j = 0; j < 2; ++j) {
        f32x4 a = conv_acc<NKB2, false>(sm.u.im.img_r, fG2, offs2, binG[j], fg);
        if (vG[j]) {
          bf16x4 pk;
#pragma unroll
          for (int q = 0; q < 4; ++q) {
            float rv = sigm(a[q] + bb[co0 + q]);
            pk[q] = f2bf(sm.sH[(co0 + q) * SS + sg[j]] * rv);
          }
          *(bf16x4*)&sm.u.im.stacked[poutG[j] + AA + co0] = pk;
        }
      }
    }
    __syncthreads();

    // ---- P3: o conv1 on stacked2 — 8 tiles / 8 waves, 1 each
    {
      const float* bb = sm.bias + 4 * CC;
      f32x4 a = conv_acc<NKB1, true>(sm.u.im.stacked, fO1, offs1, binO, fg);
      if (vO) {
        bf16x4 pk;
#pragma unroll
        for (int q = 0; q < 4; ++q) pk[q] = f2bf(fmaxf(a[q] + bb[co0 + q], 0.f));
        *(bf16x4*)&sm.u.im.img_u[poutO + co0] = pk;
      }
    }
    __syncthreads();

    // ---- P4: o conv2 -> tanh -> sO, 1 tile/wave
    {
      const float* bb = sm.bias + 5 * CC;
      f32x4 a = conv_acc<NKB2, false>(sm.u.im.img_u, fO2, offs2, binO, fg);
      if (vO) {
#pragma unroll
        for (int q = 0; q < 4; ++q)
          sm.sO[(co0 + q) * SS + sOv] = tanhfast(a[q] + bb[co0 + q]);
      }
    }
    __syncthreads();

    // ---- P5: epilogue(t) + build(t+1); globals already in registers
    {
#pragma unroll
      for (int j = 0; j < 4; ++j) if (eval[j]) {
        const int ii = eidx[j];
        float uv = sm.sU[ii], ov = sm.sO[ii], pv = sm.sH[ii];
        float pm = pv + (ov - pv) * uv;
        out_pmu[obase + ii] = pm;
        float a = avv[j];
        float at2 = xcar[j] * a + pm * (1.f - a);
        out_att[obase + ii] = at2;
        if (last) {
          out_h[(size_t)n * HH + ii] = at2;
        } else {
          float h = at2 * m2 + xnv[j] * (1.f - m2);
          sm.sH[ii] = h;
          sm.u.im.stacked[stAddr[j]] = f2bf(h);
          xcar[j] = xnv[j];
        }
      }
      if (inpV && !last) sm.u.im.stacked[inpAddr] = f2bf(pav);
    }
    __syncthreads();
  }
}

extern "C" void kernel_launch(void* const* d_in, const int* in_sizes, int n_in,
                              void* d_out, int out_size, void* d_ws, size_t ws_size,
                              hipStream_t stream)
{
  const float* x    = (const float*)d_in[0];
  const float* hxs  = (const float*)d_in[1];
  const float* att  = (const float*)d_in[2];
  const float* mks  = (const float*)d_in[3];
  const float* pact = (const float*)d_in[4];
  const float* Wr1  = (const float*)d_in[5];
  const float* br1  = (const float*)d_in[6];
  const float* Wr2  = (const float*)d_in[7];
  const float* br2  = (const float*)d_in[8];
  const float* Wu1  = (const float*)d_in[9];
  const float* bu1  = (const float*)d_in[10];
  const float* Wu2  = (const float*)d_in[11];
  const float* bu2  = (const float*)d_in[12];
  const float* Wo1  = (const float*)d_in[13];
  const float* bo1  = (const float*)d_in[14];
  const float* Wo2  = (const float*)d_in[15];
  const float* bo2  = (const float*)d_in[16];

  convgru_mfma<<<dim3(NB), dim3(NTHR), 0, stream>>>(
      x, hxs, att, mks, pact,
      Wr1, br1, Wr2, br2, Wu1, bu1, Wu2, bu2, Wo1, bo1, Wo2, bo2,
      (float*)d_out);
}